// Round 1
// baseline (180.544 us; speedup 1.0000x reference)
//
#include <hip/hip_runtime.h>

#define TB 256   // T (sequence length)
#define CC 64    // C (embed)
#define HH 64    // H (head size)

typedef __attribute__((ext_vector_type(8))) short short8;   // 8 bf16 (4 VGPRs)
typedef __attribute__((ext_vector_type(4))) float f32x4;    // MFMA C/D frag

#define MFMA16(a, b, c) __builtin_amdgcn_mfma_f32_16x16x32_bf16((a), (b), (c), 0, 0, 0)

__device__ __forceinline__ unsigned short f2bf(float f) {
    union { float f; unsigned u; } v; v.f = f;
    unsigned r = v.u + 0x7FFFu + ((v.u >> 16) & 1u);   // round-to-nearest-even
    return (unsigned short)(r >> 16);
}

__device__ __forceinline__ short8 pack8(const f32x4 a, const f32x4 b) {
    short8 r;
    r[0] = (short)f2bf(a[0]); r[1] = (short)f2bf(a[1]);
    r[2] = (short)f2bf(a[2]); r[3] = (short)f2bf(a[3]);
    r[4] = (short)f2bf(b[0]); r[5] = (short)f2bf(b[1]);
    r[6] = (short)f2bf(b[2]); r[7] = (short)f2bf(b[3]);
    return r;
}

// swizzles: q/k stored [pos][64h] (128B rows), elem ^= (pos&7)<<3
//           vT stored  [h][256c] (512B rows), elem ^= (h&7)<<3
//           p  stored  [16r][32c] (64B rows), elem ^= (r&3)<<3
__device__ __forceinline__ int swz_qk(int pos, int h) { return (pos * 64 + h) ^ ((pos & 7) << 3); }
__device__ __forceinline__ int swz_vt(int h, int c)   { return (h * 256 + c) ^ ((h & 7) << 3); }
__device__ __forceinline__ int swz_p(int r, int c)    { return (r * 32 + c) ^ ((r & 3) << 3); }

__global__ __launch_bounds__(512, 2)
void attn_fused(const float* __restrict__ x, const float* __restrict__ Wq,
                const float* __restrict__ Wk, const float* __restrict__ Wv,
                float* __restrict__ out)
{
    __shared__ __align__(16) unsigned short q_lds[TB * HH];
    __shared__ __align__(16) unsigned short k_lds[TB * HH];
    __shared__ __align__(16) unsigned short vT_lds[HH * TB];
    __shared__ __align__(16) unsigned short p_lds[8][16 * 32];

    const int b    = blockIdx.x;
    const int tid  = threadIdx.x;
    const int wave = tid >> 6;
    const int lane = tid & 63;
    const int lr   = lane & 15;   // row/col-within-16 index
    const int lg   = lane >> 4;   // k-group 0..3

    const int s_of[2] = { wave, 15 - wave };   // paired strips: balanced causal work

    // ---------- Phase A: x A-fragments for both strips (global fp32 -> bf16) ----------
    short8 xa[2][2];
#pragma unroll
    for (int sp = 0; sp < 2; ++sp) {
        const int s = s_of[sp];
        const float* xr = x + ((size_t)b * TB + s * 16 + lr) * CC;
#pragma unroll
        for (int kk = 0; kk < 2; ++kk) {
            const f32x4* p4 = (const f32x4*)(xr + kk * 32 + lg * 8);
            xa[sp][kk] = pack8(p4[0], p4[1]);
        }
    }

    // ---------- Phase B: q,k,v = x @ W^T ----------
    const float* Ws[3] = { Wq, Wk, Wv };
#pragma unroll
    for (int m = 0; m < 3; ++m) {
        short8 wb[4][2];
#pragma unroll
        for (int t = 0; t < 4; ++t)
#pragma unroll
            for (int kk = 0; kk < 2; ++kk) {
                const f32x4* p4 = (const f32x4*)(Ws[m] + (16 * t + lr) * CC + kk * 32 + lg * 8);
                wb[t][kk] = pack8(p4[0], p4[1]);
            }
#pragma unroll
        for (int sp = 0; sp < 2; ++sp) {
            const int s = s_of[sp];
            f32x4 acc[4];
#pragma unroll
            for (int t = 0; t < 4; ++t) acc[t] = (f32x4){0.f, 0.f, 0.f, 0.f};
#pragma unroll
            for (int kk = 0; kk < 2; ++kk)
#pragma unroll
                for (int t = 0; t < 4; ++t)
                    acc[t] = MFMA16(xa[sp][kk], wb[t][kk], acc[t]);

            if (m < 2) {
                unsigned short* dst = (m == 0) ? q_lds : k_lds;
#pragma unroll
                for (int t = 0; t < 4; ++t)
#pragma unroll
                    for (int reg = 0; reg < 4; ++reg) {
                        const int pos = 16 * s + 4 * lg + reg;
                        dst[swz_qk(pos, 16 * t + lr)] = f2bf(acc[t][reg]);
                    }
            } else {
#pragma unroll
                for (int t = 0; t < 4; ++t) {
                    const int h = 16 * t + lr;
                    unsigned long long u =
                          (unsigned long long)f2bf(acc[t][0])
                        | ((unsigned long long)f2bf(acc[t][1]) << 16)
                        | ((unsigned long long)f2bf(acc[t][2]) << 32)
                        | ((unsigned long long)f2bf(acc[t][3]) << 48);
                    *(unsigned long long*)&vT_lds[swz_vt(h, 16 * s + 4 * lg)] = u;
                }
            }
        }
    }
    __syncthreads();

    // ---------- Phase C: causal attention, strip by strip ----------
    const float kexp = 0.125f * 1.44269504088896f;   // scale * log2(e)
    for (int sp = 0; sp < 2; ++sp) {
        const int s = s_of[sp];
        const int ntiles = s + 1;   // causal col-tiles for this strip

        // q B-frags for this strip: lane = query row (lr), contiguous h
        short8 qb[2];
#pragma unroll
        for (int kk = 0; kk < 2; ++kk)
            qb[kk] = *(const short8*)&q_lds[swz_qk(16 * s + lr, kk * 32 + lg * 8)];

        // S^T tiles: D[m=c][n=r]; lane owns query row r=lr, 4 consecutive c per reg-quad
        f32x4 st[16];
#pragma unroll
        for (int j = 0; j < 16; ++j) {
            st[j] = (f32x4){0.f, 0.f, 0.f, 0.f};
            if (j < ntiles) {
#pragma unroll
                for (int kk = 0; kk < 2; ++kk) {
                    short8 ka = *(const short8*)&k_lds[swz_qk(16 * j + lr, kk * 32 + lg * 8)];
                    st[j] = MFMA16(ka, qb[kk], st[j]);
                }
            }
        }
        // causal mask: only the last (diagonal) tile mixes; mask c_local > r_local
#pragma unroll
        for (int j = 0; j < 16; ++j)
            if (j == ntiles - 1) {
#pragma unroll
                for (int reg = 0; reg < 4; ++reg)
                    if (4 * lg + reg > lr) st[j][reg] = -__builtin_inff();
            }

        // row max (lane-local over regs, then across the 4 c-groups)
        float mx = -__builtin_inff();
#pragma unroll
        for (int j = 0; j < 16; ++j)
            if (j < ntiles) {
#pragma unroll
                for (int reg = 0; reg < 4; ++reg) mx = fmaxf(mx, st[j][reg]);
            }
        mx = fmaxf(mx, __shfl_xor(mx, 16));
        mx = fmaxf(mx, __shfl_xor(mx, 32));

        float sm = 0.f;
#pragma unroll
        for (int j = 0; j < 16; ++j)
            if (j < ntiles) {
#pragma unroll
                for (int reg = 0; reg < 4; ++reg) {
                    float p = exp2f((st[j][reg] - mx) * kexp);
                    st[j][reg] = p;
                    sm += p;
                }
            }
        sm += __shfl_xor(sm, 16);
        sm += __shfl_xor(sm, 32);
        const float rinv = 1.0f / sm;

        // ---------- PV ----------
        f32x4 o[4];
#pragma unroll
        for (int t = 0; t < 4; ++t) o[t] = (f32x4){0.f, 0.f, 0.f, 0.f};

        unsigned short* pw = p_lds[wave];
#pragma unroll
        for (int kt = 0; kt < 8; ++kt) {
            if (2 * kt < ntiles) {
                // pack P tiles 2kt, 2kt+1 (bf16) into per-wave LDS buffer [16r][32c]
#pragma unroll
                for (int half = 0; half < 2; ++half) {
                    const int j = 2 * kt + half;
                    unsigned long long u = 0ull;
#pragma unroll
                    for (int jj = 0; jj < 16; ++jj)
                        if (jj == j && jj < ntiles) {
                            u =   (unsigned long long)f2bf(st[jj][0])
                                | ((unsigned long long)f2bf(st[jj][1]) << 16)
                                | ((unsigned long long)f2bf(st[jj][2]) << 32)
                                | ((unsigned long long)f2bf(st[jj][3]) << 48);
                        }
                    *(unsigned long long*)&pw[swz_p(lr, 16 * half + 4 * lg)] = u;
                }
                // A-frag: lane = row r=lr, 8 contiguous c
                short8 pa = *(const short8*)&pw[swz_p(lr, lg * 8)];
#pragma unroll
                for (int t = 0; t < 4; ++t) {
                    const int h = 16 * t + lr;
                    short8 vb = *(const short8*)&vT_lds[swz_vt(h, 32 * kt + lg * 8)];
                    o[t] = MFMA16(pa, vb, o[t]);
                }
            }
        }

        // scale by 1/denom (fetch per-output-row denom via lane shuffle) and store fp32
#pragma unroll
        for (int reg = 0; reg < 4; ++reg) {
            const float dn = __shfl(rinv, 4 * lg + reg);
            const int r = 16 * s + 4 * lg + reg;
#pragma unroll
            for (int t = 0; t < 4; ++t)
                out[((size_t)b * TB + r) * HH + 16 * t + lr] = o[t][reg] * dn;
        }
    }
}

extern "C" void kernel_launch(void* const* d_in, const int* in_sizes, int n_in,
                              void* d_out, int out_size, void* d_ws, size_t ws_size,
                              hipStream_t stream) {
    const float* x  = (const float*)d_in[0];
    const float* Wq = (const float*)d_in[1];
    const float* Wk = (const float*)d_in[2];
    const float* Wv = (const float*)d_in[3];
    float* out = (float*)d_out;
    const int Bn = in_sizes[0] / (TB * CC);   // 2048
    attn_fused<<<Bn, 512, 0, stream>>>(x, Wq, Wk, Wv, out);
}

// Round 3
// 152.575 us; speedup vs baseline: 1.1833x; 1.1833x over previous
//
#include <hip/hip_runtime.h>

#define TB 256   // T (sequence length)
#define CC 64    // C (embed)
#define HH 64    // H (head size)

typedef __attribute__((ext_vector_type(8))) short short8;   // 8 bf16 (4 VGPRs)
typedef __attribute__((ext_vector_type(4))) float f32x4;    // MFMA C/D frag

#define MFMA16(a, b, c) __builtin_amdgcn_mfma_f32_16x16x32_bf16((a), (b), (c), 0, 0, 0)

__device__ __forceinline__ unsigned short f2bf(float f) {
    union { float f; unsigned u; } v; v.f = f;
    unsigned r = v.u + 0x7FFFu + ((v.u >> 16) & 1u);   // round-to-nearest-even
    return (unsigned short)(r >> 16);
}

__device__ __forceinline__ short8 pack8(f32x4 a, f32x4 b) {
    short8 r;
    r[0] = (short)f2bf(a[0]); r[1] = (short)f2bf(a[1]);
    r[2] = (short)f2bf(a[2]); r[3] = (short)f2bf(a[3]);
    r[4] = (short)f2bf(b[0]); r[5] = (short)f2bf(b[1]);
    r[6] = (short)f2bf(b[2]); r[7] = (short)f2bf(b[3]);
    return r;
}

__device__ __forceinline__ unsigned long long pack4(f32x4 a) {
    return  (unsigned long long)f2bf(a[0])
         | ((unsigned long long)f2bf(a[1]) << 16)
         | ((unsigned long long)f2bf(a[2]) << 32)
         | ((unsigned long long)f2bf(a[3]) << 48);
}

// k-dim bijection used CONSISTENTLY by both operands of every MFMA:
//   QK^T:  (kk, lg, e) -> h = 16*(2*kk + (e>>2)) + 4*lg + (e&3)   [pack8 of acc quads]
//   PV:    (kt, lg, e) -> c = 16*(2*kt + (e>>2)) + 4*lg + (e&3)
__global__ __launch_bounds__(512, 4)
void attn_fused(const float* __restrict__ x, const float* __restrict__ Wq,
                const float* __restrict__ Wk, const float* __restrict__ Wv,
                float* __restrict__ out)
{
    // K fragments, frag-ready: [j=16][kk=2][lg=4][lr=16] x 16B = 32 KB (conflict-free)
    __shared__ __align__(16) short8 kf_lds[16 * 2 * 4 * 16];
    // V bf16 c-quads: [lg=4][h=64][s_swz=16] x u64 = 32 KB
    __shared__ __align__(16) unsigned long long vq_lds[4 * 64 * 16];

    const int b    = blockIdx.x;
    const int tid  = threadIdx.x;
    const int wave = tid >> 6;
    const int lane = tid & 63;
    const int lr   = lane & 15;
    const int lg   = lane >> 4;
    const int xsw  = (lr & 7) << 1;   // vq bank swizzle (even -> preserves b128 pairing)

    const int s_of[2] = { wave, 15 - wave };   // paired strips: balanced causal work

    // ---------- Phase A: x fragments (lane = pos, serves as A- and B-operand) ----------
    short8 xa[2][2];
#pragma unroll
    for (int sp = 0; sp < 2; ++sp) {
        const int s = s_of[sp];
        const float* xr = x + ((size_t)b * TB + s * 16 + lr) * CC;
#pragma unroll
        for (int kk = 0; kk < 2; ++kk) {
            const f32x4* p4 = (const f32x4*)(xr + kk * 32 + lg * 8);
            xa[sp][kk] = pack8(p4[0], p4[1]);
        }
    }

    // ---------- Phase B: q^T,k^T = W@x^T (lane=pos); v = x@W^T (lane=h) ----------
    short8 qf[2][2];
    const float* Ws[3] = { Wq, Wk, Wv };
#pragma unroll
    for (int m = 0; m < 3; ++m) {
        short8 wb[4][2];
#pragma unroll
        for (int t = 0; t < 4; ++t)
#pragma unroll
            for (int kk = 0; kk < 2; ++kk) {
                const f32x4* p4 = (const f32x4*)(Ws[m] + (16 * t + lr) * CC + kk * 32 + lg * 8);
                wb[t][kk] = pack8(p4[0], p4[1]);
            }
#pragma unroll
        for (int sp = 0; sp < 2; ++sp) {
            const int s = s_of[sp];
            f32x4 acc[4];
#pragma unroll
            for (int t = 0; t < 4; ++t) acc[t] = (f32x4){0.f, 0.f, 0.f, 0.f};
#pragma unroll
            for (int kk = 0; kk < 2; ++kk)
#pragma unroll
                for (int t = 0; t < 4; ++t)
                    acc[t] = (m < 2) ? MFMA16(wb[t][kk], xa[sp][kk], acc[t])   // W in A slot -> transposed D
                                     : MFMA16(xa[sp][kk], wb[t][kk], acc[t]);  // x in A slot -> standard D

            if (m == 0) {
                // Q stays in registers, already fragment-shaped
#pragma unroll
                for (int kk = 0; kk < 2; ++kk)
                    qf[sp][kk] = pack8(acc[2 * kk], acc[2 * kk + 1]);
            } else if (m == 1) {
#pragma unroll
                for (int kk = 0; kk < 2; ++kk)
                    kf_lds[((s * 2 + kk) * 4 + lg) * 16 + lr] = pack8(acc[2 * kk], acc[2 * kk + 1]);
            } else {
#pragma unroll
                for (int t = 0; t < 4; ++t)
                    vq_lds[(lg * 64 + 16 * t + lr) * 16 + (s ^ xsw)] = pack4(acc[t]);
            }
        }
    }
    __syncthreads();

    // ---------- Phase C: causal attention ----------
    const float kexp = 0.125f * 1.44269504088896f;   // scale * log2(e)
#pragma unroll
    for (int sp = 0; sp < 2; ++sp) {
        const int s = s_of[sp];
        const int ntiles = s + 1;

        // S^T tiles: lane owns query row r=lr; c = 16j + 4lg + reg
        f32x4 st[16];
#pragma unroll
        for (int j = 0; j < 16; ++j) {
            st[j] = (f32x4){0.f, 0.f, 0.f, 0.f};
            if (j < ntiles) {
#pragma unroll
                for (int kk = 0; kk < 2; ++kk)
                    st[j] = MFMA16(kf_lds[((j * 2 + kk) * 4 + lg) * 16 + lr], qf[sp][kk], st[j]);
            }
        }
        // causal mask on the diagonal tile (finite mask: no inf arithmetic anywhere)
#pragma unroll
        for (int j = 0; j < 16; ++j)
            if (j == ntiles - 1) {
#pragma unroll
                for (int reg = 0; reg < 4; ++reg)
                    if (4 * lg + reg > lr) st[j][reg] = -1.0e9f;
            }

        float mx = -3.0e38f;
#pragma unroll
        for (int j = 0; j < 16; ++j)
            if (j < ntiles) {
#pragma unroll
                for (int reg = 0; reg < 4; ++reg) mx = fmaxf(mx, st[j][reg]);
            }
        mx = fmaxf(mx, __shfl_xor(mx, 16));
        mx = fmaxf(mx, __shfl_xor(mx, 32));

        float sm = 0.f;
#pragma unroll
        for (int j = 0; j < 16; ++j)
            if (j < ntiles) {
#pragma unroll
                for (int reg = 0; reg < 4; ++reg) {
                    float p = exp2f((st[j][reg] - mx) * kexp);
                    st[j][reg] = p;
                    sm += p;
                }
            }
        sm += __shfl_xor(sm, 16);
        sm += __shfl_xor(sm, 32);
        const float rinv = 1.0f / sm;

        // ---------- PV: P fragments packed in-register; V fragments from vq_lds ----------
        f32x4 o[4];
#pragma unroll
        for (int t = 0; t < 4; ++t) o[t] = (f32x4){0.f, 0.f, 0.f, 0.f};

#pragma unroll
        for (int kt = 0; kt < 8; ++kt) {
            if (2 * kt < ntiles) {
                short8 pa = pack8(st[2 * kt], st[2 * kt + 1]);   // zeros beyond ntiles are benign
#pragma unroll
                for (int t = 0; t < 4; ++t) {
                    const unsigned long long* vp =
                        &vq_lds[(lg * 64 + 16 * t + lr) * 16 + ((2 * kt) ^ xsw)];
                    short8 vb = *(const short8*)vp;
                    o[t] = MFMA16(pa, vb, o[t]);
                }
            }
        }

        // scale by 1/denom and store fp32
#pragma unroll
        for (int reg = 0; reg < 4; ++reg) {
            const float dn = __shfl(rinv, 4 * lg + reg);
            const int r = 16 * s + 4 * lg + reg;
#pragma unroll
            for (int t = 0; t < 4; ++t)
                out[((size_t)b * TB + r) * HH + 16 * t + lr] = o[t][reg] * dn;
        }
    }
}

extern "C" void kernel_launch(void* const* d_in, const int* in_sizes, int n_in,
                              void* d_out, int out_size, void* d_ws, size_t ws_size,
                              hipStream_t stream) {
    const float* x  = (const float*)d_in[0];
    const float* Wq = (const float*)d_in[1];
    const float* Wk = (const float*)d_in[2];
    const float* Wv = (const float*)d_in[3];
    float* out = (float*)d_out;
    const int Bn = in_sizes[0] / (TB * CC);   // 2048
    attn_fused<<<Bn, 512, 0, stream>>>(x, Wq, Wk, Wv, out);
}

// Round 4
// 146.798 us; speedup vs baseline: 1.2299x; 1.0394x over previous
//
#include <hip/hip_runtime.h>

#define TB 256   // T (sequence length)
#define CC 64    // C (embed)
#define HH 64    // H (head size)

typedef __attribute__((ext_vector_type(8))) short short8;   // 8 bf16 (4 VGPRs)
typedef __attribute__((ext_vector_type(4))) float f32x4;    // MFMA C/D frag

#define MFMA16(a, b, c) __builtin_amdgcn_mfma_f32_16x16x32_bf16((a), (b), (c), 0, 0, 0)

// bf16 convert, round-half-up: 2 VALU/elem (add, shift); tie bias ~2^-17 relative.
__device__ __forceinline__ unsigned short f2bf(float f) {
    union { float f; unsigned u; } v; v.f = f;
    return (unsigned short)((v.u + 0x8000u) >> 16);
}

__device__ __forceinline__ short8 pack8(f32x4 a, f32x4 b) {
    short8 r;
    r[0] = (short)f2bf(a[0]); r[1] = (short)f2bf(a[1]);
    r[2] = (short)f2bf(a[2]); r[3] = (short)f2bf(a[3]);
    r[4] = (short)f2bf(b[0]); r[5] = (short)f2bf(b[1]);
    r[6] = (short)f2bf(b[2]); r[7] = (short)f2bf(b[3]);
    return r;
}

__device__ __forceinline__ unsigned long long pack4(f32x4 a) {
    return  (unsigned long long)f2bf(a[0])
         | ((unsigned long long)f2bf(a[1]) << 16)
         | ((unsigned long long)f2bf(a[2]) << 32)
         | ((unsigned long long)f2bf(a[3]) << 48);
}

// k-dim bijection used CONSISTENTLY by both operands of every MFMA:
//   QK^T:  (kk, lg, e) -> h = 16*(2*kk + (e>>2)) + 4*lg + (e&3)   [pack8 of acc quads]
//   PV:    (kt, lg, e) -> c = 16*(2*kt + (e>>2)) + 4*lg + (e&3)
__global__ __launch_bounds__(512, 4)
void attn_fused(const float* __restrict__ x, const float* __restrict__ Wq,
                const float* __restrict__ Wk, const float* __restrict__ Wv,
                float* __restrict__ out)
{
    // K fragments, frag-ready: [j=16][kk=2][lg=4][lr=16] x 16B = 32 KB (conflict-free)
    __shared__ __align__(16) short8 kf_lds[16 * 2 * 4 * 16];
    // V bf16 c-quads: [lg=4][h=64][s_swz=16] x u64 = 32 KB
    __shared__ __align__(16) unsigned long long vq_lds[4 * 64 * 16];

    const int b    = blockIdx.x;
    const int tid  = threadIdx.x;
    const int wave = tid >> 6;
    const int lane = tid & 63;
    const int lr   = lane & 15;
    const int lg   = lane >> 4;
    const int xsw  = (lr & 7) << 1;   // vq bank swizzle (even -> preserves b128 pairing)

    const int s_of[2] = { wave, 15 - wave };   // paired strips: balanced causal work

    // ---------- Phase A: x fragments (lane = pos, serves as A- and B-operand) ----------
    short8 xa[2][2];
#pragma unroll
    for (int sp = 0; sp < 2; ++sp) {
        const int s = s_of[sp];
        const float* xr = x + ((size_t)b * TB + s * 16 + lr) * CC;
#pragma unroll
        for (int kk = 0; kk < 2; ++kk) {
            const f32x4* p4 = (const f32x4*)(xr + kk * 32 + lg * 8);
            xa[sp][kk] = pack8(p4[0], p4[1]);
        }
    }

    // ---------- Phase B: q^T,k^T = W@x^T (lane=pos); v = x@W^T (lane=h) ----------
    short8 qf[2][2];
    const float* Ws[3] = { Wq, Wk, Wv };
#pragma unroll
    for (int m = 0; m < 3; ++m) {
        short8 wb[4][2];
#pragma unroll
        for (int t = 0; t < 4; ++t)
#pragma unroll
            for (int kk = 0; kk < 2; ++kk) {
                const f32x4* p4 = (const f32x4*)(Ws[m] + (16 * t + lr) * CC + kk * 32 + lg * 8);
                wb[t][kk] = pack8(p4[0], p4[1]);
            }
#pragma unroll
        for (int sp = 0; sp < 2; ++sp) {
            const int s = s_of[sp];
            f32x4 acc[4];
#pragma unroll
            for (int t = 0; t < 4; ++t) acc[t] = (f32x4){0.f, 0.f, 0.f, 0.f};
#pragma unroll
            for (int kk = 0; kk < 2; ++kk)
#pragma unroll
                for (int t = 0; t < 4; ++t)
                    acc[t] = (m < 2) ? MFMA16(wb[t][kk], xa[sp][kk], acc[t])   // W in A slot -> transposed D
                                     : MFMA16(xa[sp][kk], wb[t][kk], acc[t]);  // x in A slot -> standard D

            if (m == 0) {
                // Q stays in registers, already fragment-shaped
#pragma unroll
                for (int kk = 0; kk < 2; ++kk)
                    qf[sp][kk] = pack8(acc[2 * kk], acc[2 * kk + 1]);
            } else if (m == 1) {
#pragma unroll
                for (int kk = 0; kk < 2; ++kk)
                    kf_lds[((s * 2 + kk) * 4 + lg) * 16 + lr] = pack8(acc[2 * kk], acc[2 * kk + 1]);
            } else {
#pragma unroll
                for (int t = 0; t < 4; ++t)
                    vq_lds[(lg * 64 + 16 * t + lr) * 16 + (s ^ xsw)] = pack4(acc[t]);
            }
        }
    }
    __syncthreads();

    // ---------- Phase C: causal attention ----------
    const float kexp = 0.125f * 1.44269504088896f;   // scale * log2(e)
#pragma unroll
    for (int sp = 0; sp < 2; ++sp) {
        const int s = s_of[sp];
        const int ntiles = s + 1;

        // S^T tiles: lane owns query row r=lr; c = 16j + 4lg + reg
        f32x4 st[16];
#pragma unroll
        for (int j = 0; j < 16; ++j) {
            st[j] = (f32x4){0.f, 0.f, 0.f, 0.f};
            if (j < ntiles) {
#pragma unroll
                for (int kk = 0; kk < 2; ++kk)
                    st[j] = MFMA16(kf_lds[((j * 2 + kk) * 4 + lg) * 16 + lr], qf[sp][kk], st[j]);
            }
        }
        // causal mask on the diagonal tile (finite mask: no inf arithmetic anywhere)
#pragma unroll
        for (int j = 0; j < 16; ++j)
            if (j == ntiles - 1) {
#pragma unroll
                for (int reg = 0; reg < 4; ++reg)
                    if (4 * lg + reg > lr) st[j][reg] = -1.0e9f;
            }

        // row max: 4 parallel chains (one per reg slot), then combine
        float m0 = -3.0e38f, m1 = -3.0e38f, m2 = -3.0e38f, m3 = -3.0e38f;
#pragma unroll
        for (int j = 0; j < 16; ++j)
            if (j < ntiles) {
                m0 = fmaxf(m0, st[j][0]);
                m1 = fmaxf(m1, st[j][1]);
                m2 = fmaxf(m2, st[j][2]);
                m3 = fmaxf(m3, st[j][3]);
            }
        float mx = fmaxf(fmaxf(m0, m1), fmaxf(m2, m3));
        mx = fmaxf(mx, __shfl_xor(mx, 16));
        mx = fmaxf(mx, __shfl_xor(mx, 32));

        // p = exp2(s*kexp - mx*kexp), 4 parallel sum chains
        const float nmx = -mx * kexp;
        float s0 = 0.f, s1 = 0.f, s2 = 0.f, s3 = 0.f;
#pragma unroll
        for (int j = 0; j < 16; ++j)
            if (j < ntiles) {
                float p0 = __builtin_amdgcn_exp2f(fmaf(st[j][0], kexp, nmx));
                float p1 = __builtin_amdgcn_exp2f(fmaf(st[j][1], kexp, nmx));
                float p2 = __builtin_amdgcn_exp2f(fmaf(st[j][2], kexp, nmx));
                float p3 = __builtin_amdgcn_exp2f(fmaf(st[j][3], kexp, nmx));
                st[j][0] = p0; st[j][1] = p1; st[j][2] = p2; st[j][3] = p3;
                s0 += p0; s1 += p1; s2 += p2; s3 += p3;
            }
        float sm = (s0 + s1) + (s2 + s3);
        sm += __shfl_xor(sm, 16);
        sm += __shfl_xor(sm, 32);
        const float rinv = __builtin_amdgcn_rcpf(sm);

        // ---------- PV: P fragments packed in-register; V fragments from vq_lds ----------
        f32x4 o[4];
#pragma unroll
        for (int t = 0; t < 4; ++t) o[t] = (f32x4){0.f, 0.f, 0.f, 0.f};

#pragma unroll
        for (int kt = 0; kt < 8; ++kt) {
            if (2 * kt < ntiles) {
                short8 pa = pack8(st[2 * kt], st[2 * kt + 1]);   // zeros beyond ntiles are benign
#pragma unroll
                for (int t = 0; t < 4; ++t) {
                    const unsigned long long* vp =
                        &vq_lds[(lg * 64 + 16 * t + lr) * 16 + ((2 * kt) ^ xsw)];
                    short8 vb = *(const short8*)vp;
                    o[t] = MFMA16(pa, vb, o[t]);
                }
            }
        }

        // scale by 1/denom and store fp32
#pragma unroll
        for (int reg = 0; reg < 4; ++reg) {
            const float dn = __shfl(rinv, 4 * lg + reg);
            const int r = 16 * s + 4 * lg + reg;
#pragma unroll
            for (int t = 0; t < 4; ++t)
                out[((size_t)b * TB + r) * HH + 16 * t + lr] = o[t][reg] * dn;
        }
    }
}

extern "C" void kernel_launch(void* const* d_in, const int* in_sizes, int n_in,
                              void* d_out, int out_size, void* d_ws, size_t ws_size,
                              hipStream_t stream) {
    const float* x  = (const float*)d_in[0];
    const float* Wq = (const float*)d_in[1];
    const float* Wk = (const float*)d_in[2];
    const float* Wv = (const float*)d_in[3];
    float* out = (float*)d_out;
    const int Bn = in_sizes[0] / (TB * CC);   // 2048
    attn_fused<<<Bn, 512, 0, stream>>>(x, Wq, Wk, Wv, out);
}

// Round 5
// 88.617 us; speedup vs baseline: 2.0374x; 1.6565x over previous
//
#include <hip/hip_runtime.h>

#define TB 256   // T (sequence length)
#define CC 64    // C (embed)
#define HH 64    // H (head size)

typedef __attribute__((ext_vector_type(8))) short short8;   // 8 bf16 (4 VGPRs)
typedef __attribute__((ext_vector_type(4))) float f32x4;    // MFMA C/D frag

#define MFMA16(a, b, c) __builtin_amdgcn_mfma_f32_16x16x32_bf16((a), (b), (c), 0, 0, 0)

// bf16 convert, round-half-up: 2 VALU/elem; tie bias ~2^-17 relative (absmax-safe, proven R3).
__device__ __forceinline__ unsigned short f2bf(float f) {
    union { float f; unsigned u; } v; v.f = f;
    return (unsigned short)((v.u + 0x8000u) >> 16);
}

__device__ __forceinline__ short8 pack8(f32x4 a, f32x4 b) {
    short8 r;
    r[0] = (short)f2bf(a[0]); r[1] = (short)f2bf(a[1]);
    r[2] = (short)f2bf(a[2]); r[3] = (short)f2bf(a[3]);
    r[4] = (short)f2bf(b[0]); r[5] = (short)f2bf(b[1]);
    r[6] = (short)f2bf(b[2]); r[7] = (short)f2bf(b[3]);
    return r;
}

__device__ __forceinline__ unsigned long long pack4(f32x4 a) {
    return  (unsigned long long)f2bf(a[0])
         | ((unsigned long long)f2bf(a[1]) << 16)
         | ((unsigned long long)f2bf(a[2]) << 32)
         | ((unsigned long long)f2bf(a[3]) << 48);
}

// Pre-kernel: W -> MFMA-ready bf16 fragments (one 512-thread block, runs once per launch).
// Layout: wf[((m*4 + t)*2 + kk)*64 + lane], lane = lg*16 + lr,
// content = pack8 of W[m] row (16t+lr), cols [kk*32 + lg*8, +8)  — byte-identical to R3's wb.
__global__ __launch_bounds__(512, 1)
void pack_w(const float* __restrict__ Wq, const float* __restrict__ Wk,
            const float* __restrict__ Wv, short8* __restrict__ wf) {
    const int tid  = threadIdx.x;
    const int lane = tid & 63;
    const int lr   = lane & 15;
    const int lg   = lane >> 4;
    const int idx  = tid >> 6;        // 0..7
    const int t    = idx >> 1;
    const int kk   = idx & 1;
    const float* Ws[3] = { Wq, Wk, Wv };
#pragma unroll
    for (int m = 0; m < 3; ++m) {
        const f32x4* p4 = (const f32x4*)(Ws[m] + (16 * t + lr) * CC + kk * 32 + lg * 8);
        wf[((m * 4 + t) * 2 + kk) * 64 + lane] = pack8(p4[0], p4[1]);
    }
}

// k-dim bijection used CONSISTENTLY by both operands of every MFMA:
//   QK^T:  (kk, lg, e) -> h = 16*(2*kk + (e>>2)) + 4*lg + (e&3)
//   PV:    (kt, lg, e) -> c = 16*(2*kt + (e>>2)) + 4*lg + (e&3)
template<bool WSF>
__global__ __launch_bounds__(512, 4)
void attn_fused(const float* __restrict__ x, const float* __restrict__ Wq,
                const float* __restrict__ Wk, const float* __restrict__ Wv,
                const short8* __restrict__ wf, float* __restrict__ out)
{
    // 64 KiB shared, phase-aliased:
    //   Phase B/C: kf (32KB) + vq (32KB)   Epilogue: fp32 stage [strip16][row16][h64]
    __shared__ __align__(16) char smem[65536];
    short8* kf_lds = (short8*)smem;                                  // [16][2][4][16]
    unsigned long long* vq_lds = (unsigned long long*)(smem + 32768); // [4][64][16]
    float* stage = (float*)smem;

    const int b    = blockIdx.x;
    const int tid  = threadIdx.x;
    const int wave = tid >> 6;
    const int lane = tid & 63;
    const int lr   = lane & 15;
    const int lg   = lane >> 4;
    const int xsw  = (lr & 7) << 1;   // vq swizzle (even -> preserves b128 pairing)

    const int s_of[2] = { wave, 15 - wave };   // paired strips: balanced causal work

    // ---------- Phase A: x fragments ----------
    short8 xa[2][2];
#pragma unroll
    for (int sp = 0; sp < 2; ++sp) {
        const int s = s_of[sp];
        const float* xr = x + ((size_t)b * TB + s * 16 + lr) * CC;
#pragma unroll
        for (int kk = 0; kk < 2; ++kk) {
            const f32x4* p4 = (const f32x4*)(xr + kk * 32 + lg * 8);
            xa[sp][kk] = pack8(p4[0], p4[1]);
        }
    }

    // ---------- Phase B: q^T,k^T = W@x^T (lane=pos); v = x@W^T (lane=h) ----------
    short8 qf[2][2];
    const float* Ws[3] = { Wq, Wk, Wv };
#pragma unroll
    for (int m = 0; m < 3; ++m) {
        short8 wb[4][2];
        if constexpr (WSF) {
#pragma unroll
            for (int t = 0; t < 4; ++t)
#pragma unroll
                for (int kk = 0; kk < 2; ++kk)
                    wb[t][kk] = wf[((m * 4 + t) * 2 + kk) * 64 + lane];
        } else {
#pragma unroll
            for (int t = 0; t < 4; ++t)
#pragma unroll
                for (int kk = 0; kk < 2; ++kk) {
                    const f32x4* p4 = (const f32x4*)(Ws[m] + (16 * t + lr) * CC + kk * 32 + lg * 8);
                    wb[t][kk] = pack8(p4[0], p4[1]);
                }
        }
#pragma unroll
        for (int sp = 0; sp < 2; ++sp) {
            const int s = s_of[sp];
            f32x4 acc[4];
#pragma unroll
            for (int t = 0; t < 4; ++t) acc[t] = (f32x4){0.f, 0.f, 0.f, 0.f};
#pragma unroll
            for (int kk = 0; kk < 2; ++kk)
#pragma unroll
                for (int t = 0; t < 4; ++t)
                    acc[t] = (m < 2) ? MFMA16(wb[t][kk], xa[sp][kk], acc[t])   // W in A slot -> transposed D
                                     : MFMA16(xa[sp][kk], wb[t][kk], acc[t]);  // x in A slot -> standard D

            if (m == 0) {
#pragma unroll
                for (int kk = 0; kk < 2; ++kk)
                    qf[sp][kk] = pack8(acc[2 * kk], acc[2 * kk + 1]);
            } else if (m == 1) {
#pragma unroll
                for (int kk = 0; kk < 2; ++kk)
                    kf_lds[((s * 2 + kk) * 4 + lg) * 16 + lr] = pack8(acc[2 * kk], acc[2 * kk + 1]);
            } else {
#pragma unroll
                for (int t = 0; t < 4; ++t)
                    vq_lds[(lg * 64 + 16 * t + lr) * 16 + (s ^ xsw)] = pack4(acc[t]);
            }
        }
    }
    __syncthreads();

    // ---------- Phase C: causal attention (results kept in regs until epilogue) ----------
    const float kexp = 0.125f * 1.44269504088896f;   // scale * log2(e)
    f32x4 oo[2][4];
    float rv[2];
#pragma unroll
    for (int sp = 0; sp < 2; ++sp) {
        const int s = s_of[sp];
        const int ntiles = s + 1;

        f32x4 st[16];
#pragma unroll
        for (int j = 0; j < 16; ++j) {
            st[j] = (f32x4){0.f, 0.f, 0.f, 0.f};
            if (j < ntiles) {
#pragma unroll
                for (int kk = 0; kk < 2; ++kk)
                    st[j] = MFMA16(kf_lds[((j * 2 + kk) * 4 + lg) * 16 + lr], qf[sp][kk], st[j]);
            }
        }
#pragma unroll
        for (int j = 0; j < 16; ++j)
            if (j == ntiles - 1) {
#pragma unroll
                for (int reg = 0; reg < 4; ++reg)
                    if (4 * lg + reg > lr) st[j][reg] = -1.0e9f;
            }

        float m0 = -3.0e38f, m1 = -3.0e38f, m2 = -3.0e38f, m3 = -3.0e38f;
#pragma unroll
        for (int j = 0; j < 16; ++j)
            if (j < ntiles) {
                m0 = fmaxf(m0, st[j][0]);
                m1 = fmaxf(m1, st[j][1]);
                m2 = fmaxf(m2, st[j][2]);
                m3 = fmaxf(m3, st[j][3]);
            }
        float mx = fmaxf(fmaxf(m0, m1), fmaxf(m2, m3));
        mx = fmaxf(mx, __shfl_xor(mx, 16));
        mx = fmaxf(mx, __shfl_xor(mx, 32));

        const float nmx = -mx * kexp;
        float s0 = 0.f, s1 = 0.f, s2 = 0.f, s3 = 0.f;
#pragma unroll
        for (int j = 0; j < 16; ++j)
            if (j < ntiles) {
                float p0 = __builtin_amdgcn_exp2f(fmaf(st[j][0], kexp, nmx));
                float p1 = __builtin_amdgcn_exp2f(fmaf(st[j][1], kexp, nmx));
                float p2 = __builtin_amdgcn_exp2f(fmaf(st[j][2], kexp, nmx));
                float p3 = __builtin_amdgcn_exp2f(fmaf(st[j][3], kexp, nmx));
                st[j][0] = p0; st[j][1] = p1; st[j][2] = p2; st[j][3] = p3;
                s0 += p0; s1 += p1; s2 += p2; s3 += p3;
            }
        float sm = (s0 + s1) + (s2 + s3);
        sm += __shfl_xor(sm, 16);
        sm += __shfl_xor(sm, 32);
        rv[sp] = __builtin_amdgcn_rcpf(sm);

        f32x4 o[4];
#pragma unroll
        for (int t = 0; t < 4; ++t) o[t] = (f32x4){0.f, 0.f, 0.f, 0.f};
#pragma unroll
        for (int kt = 0; kt < 8; ++kt) {
            if (2 * kt < ntiles) {
                short8 pa = pack8(st[2 * kt], st[2 * kt + 1]);
#pragma unroll
                for (int t = 0; t < 4; ++t) {
                    const unsigned long long* vp =
                        &vq_lds[(lg * 64 + 16 * t + lr) * 16 + ((2 * kt) ^ xsw)];
                    short8 vb = *(const short8*)vp;
                    o[t] = MFMA16(pa, vb, o[t]);
                }
            }
        }
#pragma unroll
        for (int t = 0; t < 4; ++t) oo[sp][t] = o[t];
    }

    // ---------- Epilogue: LDS restage (kf/vq dead) -> coalesced dwordx4 stores ----------
    __syncthreads();
#pragma unroll
    for (int sp = 0; sp < 2; ++sp) {
        const int s = s_of[sp];
        float dn[4];
#pragma unroll
        for (int reg = 0; reg < 4; ++reg) dn[reg] = __shfl(rv[sp], 4 * lg + reg);
#pragma unroll
        for (int t = 0; t < 4; ++t)
#pragma unroll
            for (int reg = 0; reg < 4; ++reg) {
                const int row = 4 * lg + reg;                    // query row within strip
                const int col = (16 * t + lr) ^ (lg << 4);       // XOR key = row>>2 = lg
                stage[(s * 16 + row) * 64 + col] = oo[sp][t][reg] * dn[reg];
            }
    }
    // own-wave data only: compiler inserts the lgkmcnt wait for the ds_write->ds_read dep
#pragma unroll
    for (int sp = 0; sp < 2; ++sp) {
        const int s = s_of[sp];
#pragma unroll
        for (int i = 0; i < 4; ++i) {
            const int row = 4 * i + lg;
            const int col = (4 * lr) ^ (i << 4);                 // XOR key = row>>2 = i
            f32x4 vv = *(const f32x4*)&stage[(s * 16 + row) * 64 + col];
            *(f32x4*)&out[((size_t)b * TB + 16 * s + row) * HH + 4 * lr] = vv;
        }
    }
}

extern "C" void kernel_launch(void* const* d_in, const int* in_sizes, int n_in,
                              void* d_out, int out_size, void* d_ws, size_t ws_size,
                              hipStream_t stream) {
    const float* x  = (const float*)d_in[0];
    const float* Wq = (const float*)d_in[1];
    const float* Wk = (const float*)d_in[2];
    const float* Wv = (const float*)d_in[3];
    float* out = (float*)d_out;
    const int Bn = in_sizes[0] / (TB * CC);   // 2048
    if (ws_size >= 3 * 4 * 2 * 64 * sizeof(short8)) {
        short8* wf = (short8*)d_ws;
        pack_w<<<1, 512, 0, stream>>>(Wq, Wk, Wv, wf);
        attn_fused<true><<<Bn, 512, 0, stream>>>(x, Wq, Wk, Wv, wf, out);
    } else {
        attn_fused<false><<<Bn, 512, 0, stream>>>(x, Wq, Wk, Wv, nullptr, out);
    }
}